// Round 6
// baseline (238.904 us; speedup 1.0000x reference)
//
#include <hip/hip_runtime.h>
#include <float.h>

#define NPTS 8192
#define MPTS 8192
#define FDIM 256

#define BM 256
#define BN 256
#define BK 32
#define KSTEPS (FDIM / BK)     /* 8 */
#define TCT (MPTS / BN)        /* 32 column tiles */
#define TRT (NPTS / BM)        /* 32 row tiles */

typedef unsigned short ushort_t;
typedef unsigned int u32;
typedef __attribute__((ext_vector_type(8))) short short8;
typedef __attribute__((ext_vector_type(4))) float floatx4;

// ---- top-2-by-similarity (proven round 8): select on RAW s (max); clamp and
// sqrt applied only at the ratio test. Any orderings-could-differ case forces
// d1==d2 -> ratio==1 -> ok=false under RT=1.0 -> decisions unaffected.
struct T2 { float s1, s2; int i1; };   // s1 >= s2

__device__ __forceinline__ T2 t2_sent() { T2 a; a.s1 = -FLT_MAX; a.s2 = -FLT_MAX; a.i1 = 0; return a; }

__device__ __forceinline__ T2 t2_merge(T2 a, T2 b) {
    T2 r;
    r.s1 = fmaxf(a.s1, b.s1);
    r.i1 = (b.s1 > a.s1) ? b.i1 : a.i1;
    r.s2 = fmaxf(fminf(a.s1, b.s1), fmaxf(a.s2, b.s2));
    return r;
}
__device__ __forceinline__ T2 t2_make4(float v0, float v1, float v2, float v3,
                                       int i0, int i1_, int i2, int i3) {
    float lo01 = fminf(v0, v1), hi01 = fmaxf(v0, v1);
    float lo23 = fminf(v2, v3), hi23 = fmaxf(v2, v3);
    int a01 = (v1 > v0) ? i1_ : i0;
    int a23 = (v3 > v2) ? i3 : i2;
    T2 r;
    r.s1 = fmaxf(hi01, hi23);
    r.i1 = (hi23 > hi01) ? a23 : a01;
    r.s2 = fmaxf(fminf(hi01, hi23), fmaxf(lo01, lo23));
    return r;
}
__device__ __forceinline__ float4 t2_pack(T2 a) {
    return make_float4(a.s1, a.s2, __int_as_float(a.i1), 0.0f);
}
__device__ __forceinline__ T2 t2_unpack(float4 v) {
    T2 a; a.s1 = v.x; a.s2 = v.y; a.i1 = __float_as_int(v.z); return a;
}
__device__ __forceinline__ T2 t2_shfl_xor(T2 a, int m) {
    T2 r; r.s1 = __shfl_xor(a.s1, m); r.s2 = __shfl_xor(a.s2, m); r.i1 = __shfl_xor(a.i1, m);
    return r;
}

__device__ __forceinline__ float bf2f(ushort_t u) {
    union { u32 i; float f; } v; v.i = ((u32)u) << 16; return v.f;
}
__device__ __forceinline__ ushort_t f2bf_rtne(float x) {
    u32 u = __float_as_uint(x);
    u32 r = u + 0x7FFFu + ((u >> 16) & 1u);
    return (ushort_t)(r >> 16);
}

// -------- fused transpose + hi/lo split (unchanged, proven) --------
__global__ __launch_bounds__(256) void transpose_split(
    const float* __restrict__ s0, const float* __restrict__ s1,
    ushort_t* __restrict__ hi0, ushort_t* __restrict__ lo0,
    ushort_t* __restrict__ hi1, ushort_t* __restrict__ lo1)
{
    __shared__ ushort_t hiS[64][66];
    __shared__ ushort_t loS[64][66];
    const float* src = blockIdx.z ? s1 : s0;
    ushort_t* hiT = blockIdx.z ? hi1 : hi0;
    ushort_t* loT = blockIdx.z ? lo1 : lo0;
    const int t = threadIdx.x;
    const int n0 = blockIdx.x * 64, f0 = blockIdx.y * 64;

#pragma unroll
    for (int p = 0; p < 4; p++) {
        int fl = (t >> 4) + p * 16;          // feature row 0..63
        int nl = (t & 15) * 4;               // 4 consecutive points
        float4 x = *(const float4*)&src[(size_t)(f0 + fl) * NPTS + n0 + nl];
        float xs[4] = {x.x, x.y, x.z, x.w};
#pragma unroll
        for (int e = 0; e < 4; e++) {
            ushort_t hb = f2bf_rtne(xs[e]);
            ushort_t lb = f2bf_rtne(xs[e] - bf2f(hb));
            hiS[nl + e][fl] = hb;            // 66-stride: 2-way banks (free)
            loS[nl + e][fl] = lb;
        }
    }
    __syncthreads();
#pragma unroll
    for (int p = 0; p < 8; p++) {
        int nl = (t >> 5) + p * 8;
        int fp = (t & 31) * 2;
        u32 hw = (u32)hiS[nl][fp] | ((u32)hiS[nl][fp + 1] << 16);
        u32 lw = (u32)loS[nl][fp] | ((u32)loS[nl][fp + 1] << 16);
        size_t o = (size_t)(n0 + nl) * FDIM + f0 + fp;
        *(u32*)&hiT[o] = hw;
        *(u32*)&loT[o] = lw;
    }
}

#define GLDS(g, l) __builtin_amdgcn_global_load_lds( \
    (const __attribute__((address_space(1))) void*)(g), \
    (__attribute__((address_space(3))) void*)(l), 16, 0, 0)

// -------- 256x256 double-buffered phase-split MFMA GEMM + top-2 --------
// LDS: 2 buffers x 64KB; each buffer: Ah(+0) Bh(+16K) Al(+32K) Bl(+48K),
// each 256 rows x 32 k bf16 (64-B rows, 4 x 16B chunks).
// Chunk swizzle: pos = g ^ ((row>>1)&3) -> uniform 8 dwords/bank on
// ds_read_b128 (verified round 2: conflicts 9.57M -> 3.28M, ~3% residual).
// Register budget (round-3 fix): under __launch_bounds__(512,2) the unified
// 256-reg file splits 128 AGPR (acc) + 128 VGPR. Keep VGPR-side peak under
// 128 by processing B-fragments in j-halves (bh/bl[2] reused) -> frag live
// 48 dwords, no scratch. Per-cell accumulation order (k asc, hh/hl/lh)
// unchanged -> bit-identical output.
#define STAGE(k0v, bufp, cc) do { \
    int _so = srcOff[cc] + (k0v); \
    char* _lb = (bufp) + ldsOff[cc]; \
    GLDS(bAh + _so, _lb); \
    GLDS(bBh + _so, _lb + 16384); \
    GLDS(bAl + _so, _lb + 32768); \
    GLDS(bBl + _so, _lb + 49152); \
} while (0)

#define READ_A(Pb, H) do { \
    _Pragma("unroll") for (int i = 0; i < 4; i++) { \
        ah[i] = *(const short8*)((Pb) + aBase + ((H) * 4 + i) * 1024); \
        al[i] = *(const short8*)((Pb) + 32768 + aBase + ((H) * 4 + i) * 1024); \
    } \
} while (0)

#define READ_B2(Pb, J0) do { \
    _Pragma("unroll") for (int jj = 0; jj < 2; jj++) { \
        bh[jj] = *(const short8*)((Pb) + 16384 + bBase + ((J0) + jj) * 1024); \
        bl[jj] = *(const short8*)((Pb) + 49152 + bBase + ((J0) + jj) * 1024); \
    } \
} while (0)

#define MFMA8(IOFF, J0) do { \
    _Pragma("unroll") for (int i = 0; i < 4; i++) \
    _Pragma("unroll") for (int jj = 0; jj < 2; jj++) { \
        acc[(IOFF) + i][(J0) + jj] = __builtin_amdgcn_mfma_f32_16x16x32_bf16(ah[i], bh[jj], acc[(IOFF) + i][(J0) + jj], 0, 0, 0); \
        acc[(IOFF) + i][(J0) + jj] = __builtin_amdgcn_mfma_f32_16x16x32_bf16(ah[i], bl[jj], acc[(IOFF) + i][(J0) + jj], 0, 0, 0); \
        acc[(IOFF) + i][(J0) + jj] = __builtin_amdgcn_mfma_f32_16x16x32_bf16(al[i], bh[jj], acc[(IOFF) + i][(J0) + jj], 0, 0, 0); \
    } \
} while (0)

#define PHASE(Pb, H) do { \
    READ_A(Pb, H); \
    READ_B2(Pb, 0); \
    asm volatile("s_waitcnt lgkmcnt(0)" ::: "memory"); \
    __builtin_amdgcn_sched_barrier(0); \
    __builtin_amdgcn_s_setprio(1); \
    MFMA8((H) * 4, 0); \
    __builtin_amdgcn_s_setprio(0); \
    READ_B2(Pb, 2); \
    asm volatile("s_waitcnt lgkmcnt(0)" ::: "memory"); \
    __builtin_amdgcn_sched_barrier(0); \
    __builtin_amdgcn_s_setprio(1); \
    MFMA8((H) * 4, 2); \
    __builtin_amdgcn_s_setprio(0); \
} while (0)

#define KSTEP(ksv, Pb, Qb) do { \
    const int kn_ = ((ksv) + 1) * BK; \
    STAGE(kn_, Qb, 0); \
    asm volatile("s_waitcnt vmcnt(4)" ::: "memory"); \
    __builtin_amdgcn_s_barrier(); \
    PHASE(Pb, 0); \
    __builtin_amdgcn_s_barrier(); \
    STAGE(kn_, Qb, 1); \
    PHASE(Pb, 1); \
    __builtin_amdgcn_s_barrier(); \
} while (0)

__global__ __launch_bounds__(512, 2) void gemm_top2(
    const ushort_t* __restrict__ hiA, const ushort_t* __restrict__ loA,
    const ushort_t* __restrict__ hiB, const ushort_t* __restrict__ loB,
    float4* __restrict__ rowPart, float4* __restrict__ colPart)
{
    __shared__ char smem[131072];
    const int t = threadIdx.x;
    const int lane = t & 63, lc = lane & 15, q = lane >> 4;
    const int w = t >> 6, wx = w & 3, wy = w >> 2;   // 4x col-waves, 2x row-waves
    const int ctile = blockIdx.x, rtile = blockIdx.y;
    const int n0 = rtile * BM, m0 = ctile * BN;

    floatx4 acc[8][4];
#pragma unroll
    for (int i = 0; i < 8; i++)
#pragma unroll
        for (int j = 0; j < 4; j++) acc[i][j] = (floatx4)0.0f;

    // staging map: chunk L = cc*512 + t -> row = L>>2, pos = L&3,
    // global chunk g = pos ^ ((row>>1)&3); LDS dest = L*16 B (lane-contig).
    int srcOff[2], ldsOff[2];
#pragma unroll
    for (int cc = 0; cc < 2; cc++) {
        int L = cc * 512 + t;
        int row = L >> 2;
        int g = (L & 3) ^ ((L >> 3) & 3);
        srcOff[cc] = row * FDIM + g * 8;
        ldsOff[cc] = L * 16;
    }
    const ushort_t* bAh = hiA + (size_t)n0 * FDIM;
    const ushort_t* bAl = loA + (size_t)n0 * FDIM;
    const ushort_t* bBh = hiB + (size_t)m0 * FDIM;
    const ushort_t* bBl = loB + (size_t)m0 * FDIM;

    // fragment byte offsets: row*64 + (q ^ ((row>>1)&3))*16; for row=16m+lc
    // (row>>1)&3 == (lc>>1)&3, wave-invariant per lane.
    const int xa = (q ^ ((lc >> 1) & 3)) * 16;
    const int aBase = (wy * 128 + lc) * 64 + xa;     // + i*1024 per row-frag
    const int bBase = (wx * 64 + lc) * 64 + xa;      // + j*1024 per col-frag

    short8 ah[4], al[4], bh[2], bl[2];

    char* buf0 = smem;
    char* buf1 = smem + 65536;
    STAGE(0, buf0, 0);
    STAGE(0, buf0, 1);
#pragma unroll 1
    for (int kp = 0; kp < 3; kp++) {
        KSTEP(2 * kp, buf0, buf1);
        KSTEP(2 * kp + 1, buf1, buf0);
    }
    KSTEP(6, buf0, buf1);
    {   // last K-step (ks=7): tile already fully staged, drain and compute
        char* Pb = buf1;
        asm volatile("s_waitcnt vmcnt(0)" ::: "memory");
        __builtin_amdgcn_s_barrier();
        PHASE(Pb, 0);
        PHASE(Pb, 1);
    }
    __syncthreads();

    // ---- epilogue: C/D layout row = q*4+reg, col = lane&15 (verified) ----
    float4* redC = (float4*)smem;                    // 256 cols x 2 wy = 8 KB
    {
        T2 colT[4];
#pragma unroll
        for (int j = 0; j < 4; j++) colT[j] = t2_sent();
#pragma unroll
        for (int i = 0; i < 8; i++) {
            const int rb = n0 + wy * 128 + i * 16 + q * 4;
#pragma unroll
            for (int j = 0; j < 4; j++)
                colT[j] = t2_merge(colT[j],
                    t2_make4(acc[i][j][0], acc[i][j][1], acc[i][j][2], acc[i][j][3],
                             rb, rb + 1, rb + 2, rb + 3));
        }
#pragma unroll
        for (int j = 0; j < 4; j++) {
            colT[j] = t2_merge(colT[j], t2_shfl_xor(colT[j], 16));
            colT[j] = t2_merge(colT[j], t2_shfl_xor(colT[j], 32));
            if (q == 0) redC[(wx * 64 + j * 16 + lc) * 2 + wy] = t2_pack(colT[j]);
        }
    }
    __syncthreads();
    if (t < 256) {
        T2 m = t2_unpack(redC[t * 2 + 0]);
        m = t2_merge(m, t2_unpack(redC[t * 2 + 1]));
        colPart[(size_t)rtile * MPTS + m0 + t] = t2_pack(m);
    }

    // rows: two LDS rounds by wy; 128 rows x 64 partials, bank-spread slots
    float* scrS1 = (float*)smem;                     // 128*65*4 = 33280 B
    float* scrS2 = (float*)(smem + 33280);
    int*   scrI  = (int*)(smem + 66560);             // ends 99840 < 128K
    const int cb = m0 + wx * 64 + lc;
    const int pp = wx * 16 + lc;                     // partial index 0..63
#pragma unroll
    for (int round = 0; round < 2; round++) {
        __syncthreads();
        if (wy == round) {
#pragma unroll
            for (int i = 0; i < 8; i++)
#pragma unroll
                for (int r = 0; r < 4; r++) {
                    int row = i * 16 + q * 4 + r;    // 0..127
                    T2 v = t2_make4(acc[i][0][r], acc[i][1][r], acc[i][2][r], acc[i][3][r],
                                    cb, cb + 16, cb + 32, cb + 48);
                    int slot = row * 65 + ((pp + row) & 63);
                    scrS1[slot] = v.s1; scrS2[slot] = v.s2; scrI[slot] = v.i1;
                }
        }
        __syncthreads();
        {
            int row = t >> 2, chunk = t & 3;         // 128 rows x 4 readers
            T2 a = t2_sent();
#pragma unroll
            for (int s = 0; s < 16; s++) {
                int slot = row * 65 + ((((chunk << 4) | s) + row) & 63);
                T2 b; b.s1 = scrS1[slot]; b.s2 = scrS2[slot]; b.i1 = scrI[slot];
                a = t2_merge(a, b);
            }
            a = t2_merge(a, t2_shfl_xor(a, 1));
            a = t2_merge(a, t2_shfl_xor(a, 2));
            if (chunk == 0)
                rowPart[(size_t)ctile * NPTS + n0 + round * 128 + row] = t2_pack(a);
        }
    }
}

// -------- fused final reduce (round-10 proven; tile count 64 -> 32) --------
__global__ __launch_bounds__(256) void reduce_final(
    const float4* __restrict__ rowPart, const float4* __restrict__ colPart,
    float* __restrict__ out)
{
    __shared__ float4 sh[4][64];
    __shared__ int shFwd[64];
    __shared__ int shOk[64];
    const int t = threadIdx.x, nl = t & 63, sub = t >> 6;
    const int n = blockIdx.x * 64 + nl;

    T2 a = t2_sent();
#pragma unroll
    for (int k = 0; k < 8; k++)
        a = t2_merge(a, t2_unpack(rowPart[(size_t)(sub * 8 + k) * NPTS + n]));
    sh[sub][nl] = t2_pack(a);
    __syncthreads();
    if (t < 64) {
        T2 r = t2_unpack(sh[0][t]);
        r = t2_merge(r, t2_unpack(sh[1][t]));
        r = t2_merge(r, t2_unpack(sh[2][t]));
        r = t2_merge(r, t2_unpack(sh[3][t]));
        float c1 = fmaxf(1.0f - r.s1, 1e-6f), c2 = fmaxf(1.0f - r.s2, 1e-6f);
        float d1 = 1.414213f * sqrtf(c1), d2 = 1.414213f * sqrtf(c2);
        shFwd[t] = r.i1;
        shOk[t]  = ((d1 / d2) < 1.0f) ? 1 : 0;   // exact ref ratio test, RT=1.0
    }
    __syncthreads();
    const int fw = shFwd[nl];
    T2 c = t2_sent();
#pragma unroll
    for (int k = 0; k < 8; k++)
        c = t2_merge(c, t2_unpack(colPart[(size_t)(sub * 8 + k) * MPTS + fw]));
    sh[sub][nl] = t2_pack(c);
    __syncthreads();
    if (t < 64) {
        T2 r = t2_unpack(sh[0][t]);
        r = t2_merge(r, t2_unpack(sh[1][t]));
        r = t2_merge(r, t2_unpack(sh[2][t]));
        r = t2_merge(r, t2_unpack(sh[3][t]));
        float c1 = fmaxf(1.0f - r.s1, 1e-6f), c2 = fmaxf(1.0f - r.s2, 1e-6f);
        float d1 = 1.414213f * sqrtf(c1), d2 = 1.414213f * sqrtf(c2);
        bool bok = (d1 / d2) < 1.0f;
        int nn = blockIdx.x * 64 + t;
        bool mutual = (shOk[t] != 0) && bok && (r.i1 == nn);
        int idx0 = mutual ? shFwd[t] : -1;
        out[nn]             = (float)idx0;                // indices0
        out[NPTS + nn]      = -1.0f;                      // matches1 (all -1)
        out[2 * NPTS + nn]  = (idx0 > 0) ? 1.0f : 0.0f;   // mscores0 (strict >0 ref quirk)
        out[3 * NPTS + nn]  = 0.0f;                       // mscores1
    }
}

extern "C" void kernel_launch(void* const* d_in, const int* in_sizes, int n_in,
                              void* d_out, int out_size, void* d_ws, size_t ws_size,
                              hipStream_t stream)
{
    const float* d0 = (const float*)d_in[0];   // [1, 256, 8192] f32
    const float* d1 = (const float*)d_in[1];   // [1, 256, 8192] f32

    char* ws = (char*)d_ws;
    const size_t matB = (size_t)NPTS * FDIM * sizeof(ushort_t);      // 4 MB
    ushort_t* hiA = (ushort_t*)(ws);
    ushort_t* loA = (ushort_t*)(ws + matB);
    ushort_t* hiB = (ushort_t*)(ws + 2 * matB);
    ushort_t* loB = (ushort_t*)(ws + 3 * matB);
    char* p = ws + 4 * matB;
    const size_t rowBytes = (size_t)TCT * NPTS * sizeof(float4);     // 4 MB
    float4* rowPart = (float4*)p;
    float4* colPart = (float4*)(p + rowBytes);

    dim3 gt(NPTS / 64, FDIM / 64, 2);
    transpose_split<<<gt, 256, 0, stream>>>(d0, d1, hiA, loA, hiB, loB);

    dim3 g1(TCT, TRT);   // 32 x 32 blocks of 512 threads
    gemm_top2<<<g1, 512, 0, stream>>>(hiA, loA, hiB, loB, rowPart, colPart);
    reduce_final<<<NPTS / 64, 256, 0, stream>>>(rowPart, colPart, (float*)d_out);
}

// Round 8
// 191.940 us; speedup vs baseline: 1.2447x; 1.2447x over previous
//
#include <hip/hip_runtime.h>
#include <float.h>

#define NPTS 8192
#define MPTS 8192
#define FDIM 256

#define BM 128
#define BN 128
#define BK 32
#define TCT (MPTS / BN)   /* 64 column tiles */
#define TRT (NPTS / BM)   /* 64 row tiles */

typedef unsigned short ushort_t;
typedef unsigned int u32;
typedef __attribute__((ext_vector_type(8))) short short8;
typedef __attribute__((ext_vector_type(4))) float floatx4;

// ---- top-2-by-similarity (proven): select on RAW s (max); clamp and sqrt
// applied only at the ratio test.
struct T2 { float s1, s2; int i1; };   // s1 >= s2

__device__ __forceinline__ T2 t2_sent() { T2 a; a.s1 = -FLT_MAX; a.s2 = -FLT_MAX; a.i1 = 0; return a; }

__device__ __forceinline__ T2 t2_merge(T2 a, T2 b) {
    T2 r;
    r.s1 = fmaxf(a.s1, b.s1);
    r.i1 = (b.s1 > a.s1) ? b.i1 : a.i1;
    r.s2 = fmaxf(fminf(a.s1, b.s1), fmaxf(a.s2, b.s2));
    return r;
}
__device__ __forceinline__ T2 t2_make4(float v0, float v1, float v2, float v3,
                                       int i0, int i1_, int i2, int i3) {
    float lo01 = fminf(v0, v1), hi01 = fmaxf(v0, v1);
    float lo23 = fminf(v2, v3), hi23 = fmaxf(v2, v3);
    int a01 = (v1 > v0) ? i1_ : i0;
    int a23 = (v3 > v2) ? i3 : i2;
    T2 r;
    r.s1 = fmaxf(hi01, hi23);
    r.i1 = (hi23 > hi01) ? a23 : a01;
    r.s2 = fmaxf(fminf(hi01, hi23), fmaxf(lo01, lo23));
    return r;
}
__device__ __forceinline__ float4 t2_pack(T2 a) {
    return make_float4(a.s1, a.s2, __int_as_float(a.i1), 0.0f);
}
__device__ __forceinline__ T2 t2_unpack(float4 v) {
    T2 a; a.s1 = v.x; a.s2 = v.y; a.i1 = __float_as_int(v.z); return a;
}
__device__ __forceinline__ T2 t2_shfl_xor(T2 a, int m) {
    T2 r; r.s1 = __shfl_xor(a.s1, m); r.s2 = __shfl_xor(a.s2, m); r.i1 = __shfl_xor(a.i1, m);
    return r;
}

__device__ __forceinline__ float bf2f(ushort_t u) {
    union { u32 i; float f; } v; v.i = ((u32)u) << 16; return v.f;
}
__device__ __forceinline__ ushort_t f2bf_rtne(float x) {
    u32 u = __float_as_uint(x);
    u32 r = u + 0x7FFFu + ((u >> 16) & 1u);
    return (ushort_t)(r >> 16);
}

// -------- fused transpose + hi/lo split (round-0 verbatim, proven) --------
__global__ __launch_bounds__(256) void transpose_split(
    const float* __restrict__ s0, const float* __restrict__ s1,
    ushort_t* __restrict__ hi0, ushort_t* __restrict__ lo0,
    ushort_t* __restrict__ hi1, ushort_t* __restrict__ lo1)
{
    __shared__ ushort_t hiS[64][66];
    __shared__ ushort_t loS[64][66];
    const float* src = blockIdx.z ? s1 : s0;
    ushort_t* hiT = blockIdx.z ? hi1 : hi0;
    ushort_t* loT = blockIdx.z ? lo1 : lo0;
    const int t = threadIdx.x;
    const int n0 = blockIdx.x * 64, f0 = blockIdx.y * 64;

#pragma unroll
    for (int p = 0; p < 4; p++) {
        int fl = (t >> 4) + p * 16;          // feature row 0..63
        int nl = (t & 15) * 4;               // 4 consecutive points
        float4 x = *(const float4*)&src[(size_t)(f0 + fl) * NPTS + n0 + nl];
        float xs[4] = {x.x, x.y, x.z, x.w};
#pragma unroll
        for (int e = 0; e < 4; e++) {
            ushort_t hb = f2bf_rtne(xs[e]);
            ushort_t lb = f2bf_rtne(xs[e] - bf2f(hb));
            hiS[nl + e][fl] = hb;            // 66-stride: 2-way banks (free)
            loS[nl + e][fl] = lb;
        }
    }
    __syncthreads();
#pragma unroll
    for (int p = 0; p < 8; p++) {
        int nl = (t >> 5) + p * 8;
        int fp = (t & 31) * 2;
        u32 hw = (u32)hiS[nl][fp] | ((u32)hiS[nl][fp + 1] << 16);
        u32 lw = (u32)loS[nl][fp] | ((u32)loS[nl][fp + 1] << 16);
        size_t o = (size_t)(n0 + nl) * FDIM + f0 + fp;
        *(u32*)&hiT[o] = hw;
        *(u32*)&loT[o] = lw;
    }
}

#define GLDS(g, l) __builtin_amdgcn_global_load_lds( \
    (const __attribute__((address_space(1))) void*)(g), \
    (__attribute__((address_space(3))) void*)(l), 16, 0, 0)

// -------- 128x128 MFMA GEMM + top-2, BK=32 DOUBLE-buffered (round 7) ------
// Same 64 KB LDS as the proven single-buffer BK=64 kernel -> 2 blocks/CU
// retained (cross-block overlap, the measured 38%-util mechanism). Change:
// next K-slice's 8 GLDS issue a full K-step (~2.4k cyc) ahead; one counted
// s_waitcnt vmcnt(8) per step (never 0 in-loop) so the stage stall that the
// old __syncthreads-vmcnt(0) exposed 4x/block is now hidden under MFMAs.
// Buffer: Ah(+0) Bh(+8K) Al(+16K) Bl(+24K), 128 rows x 32 k (64-B rows,
// 4 x 16B chunks). Chunk swizzle pos = g ^ ((row>>1)&3): uniform 2-way
// bank access on ds_read_b128 (validated round 2: conflict counter fell
// to ~3% residual with this exact pattern).
#define STAGE(k0v, bufp) do { \
    _Pragma("unroll") for (int cc = 0; cc < 2; cc++) { \
        int _so = srcOff[cc] + (k0v); \
        char* _lb = (bufp) + ldsOff[cc]; \
        GLDS(bAh + _so, _lb); \
        GLDS(bBh + _so, _lb + 8192); \
        GLDS(bAl + _so, _lb + 16384); \
        GLDS(bBl + _so, _lb + 24576); \
    } \
} while (0)

#define READ_ALL(Pb) do { \
    _Pragma("unroll") for (int i = 0; i < 4; i++) { \
        ah[i] = *(const short8*)((Pb) + aoff[i]); \
        al[i] = *(const short8*)((Pb) + 16384 + aoff[i]); \
        bh[i] = *(const short8*)((Pb) + 8192 + boff[i]); \
        bl[i] = *(const short8*)((Pb) + 24576 + boff[i]); \
    } \
} while (0)

#define MFMA48 do { \
    _Pragma("unroll") for (int i = 0; i < 4; i++) \
    _Pragma("unroll") for (int j = 0; j < 4; j++) { \
        acc[i][j] = __builtin_amdgcn_mfma_f32_16x16x32_bf16(ah[i], bh[j], acc[i][j], 0, 0, 0); \
        acc[i][j] = __builtin_amdgcn_mfma_f32_16x16x32_bf16(ah[i], bl[j], acc[i][j], 0, 0, 0); \
        acc[i][j] = __builtin_amdgcn_mfma_f32_16x16x32_bf16(al[i], bh[j], acc[i][j], 0, 0, 0); \
    } \
} while (0)

#define KSTEP(ksv, Pb, Qb) do { \
    STAGE(((ksv) + 1) * BK, Qb); \
    asm volatile("s_waitcnt vmcnt(8)" ::: "memory"); \
    __builtin_amdgcn_s_barrier(); \
    READ_ALL(Pb); \
    asm volatile("s_waitcnt lgkmcnt(0)" ::: "memory"); \
    __builtin_amdgcn_sched_barrier(0); \
    MFMA48; \
    __builtin_amdgcn_sched_barrier(0); \
    __builtin_amdgcn_s_barrier(); \
} while (0)

__global__ __launch_bounds__(256, 2) void gemm_top2(
    const ushort_t* __restrict__ hiA, const ushort_t* __restrict__ loA,
    const ushort_t* __restrict__ hiB, const ushort_t* __restrict__ loB,
    float4* __restrict__ rowPart, float4* __restrict__ colPart)
{
    __shared__ char smem[65536];
    // epilogue aliases (staging dead after K-loop + barrier):
    float* scrS1 = (float*)smem;                    // 64*33*4 = 8448 B
    float* scrS2 = (float*)(smem + 8448);
    int*   scrI  = (int*)(smem + 16896);            // ends 25344
    float4* redC = (float4*)(smem + 25600);         // 128*2*16 = 4096 B

    const int t = threadIdx.x;
    const int lane = t & 63, lc = lane & 15, q = lane >> 4;
    const int w = t >> 6, wx = w & 1, wy = w >> 1;
    const int ctile = blockIdx.x, rtile = blockIdx.y;
    const int n0 = rtile * BM, m0 = ctile * BN;

    floatx4 acc[4][4];
#pragma unroll
    for (int i = 0; i < 4; i++)
#pragma unroll
        for (int j = 0; j < 4; j++) acc[i][j] = (floatx4)0.0f;

    // staging map: chunk L = cc*256 + t -> row = L>>2, pos = L&3,
    // global chunk g = pos ^ ((row>>1)&3); LDS dest = L*16 B (lane-contig).
    int srcOff[2], ldsOff[2];
#pragma unroll
    for (int cc = 0; cc < 2; cc++) {
        int L = cc * 256 + t;
        int row = L >> 2;
        int g = (L & 3) ^ ((L >> 3) & 3);
        srcOff[cc] = row * FDIM + g * 8;
        ldsOff[cc] = L * 16;
    }
    const ushort_t* bAh = hiA + (size_t)n0 * FDIM;
    const ushort_t* bAl = loA + (size_t)n0 * FDIM;
    const ushort_t* bBh = hiB + (size_t)m0 * FDIM;
    const ushort_t* bBl = loB + (size_t)m0 * FDIM;

    // fragment byte offsets: row*64 + (q ^ ((row>>1)&3))*16; row = 16m+lc so
    // (row>>1)&3 == (lc>>1)&3, wave-invariant per lane.
    const int xa = (q ^ ((lc >> 1) & 3)) * 16;
    int aoff[4], boff[4];
#pragma unroll
    for (int i = 0; i < 4; i++) {
        aoff[i] = (wy * 64 + i * 16 + lc) * 64 + xa;
        boff[i] = (wx * 64 + i * 16 + lc) * 64 + xa;
    }

    short8 ah[4], al[4], bh[4], bl[4];

    char* buf0 = smem;
    char* buf1 = smem + 32768;
    STAGE(0, buf0);
#pragma unroll 1
    for (int kp = 0; kp < 3; kp++) {
        KSTEP(2 * kp, buf0, buf1);
        KSTEP(2 * kp + 1, buf1, buf0);
    }
    KSTEP(6, buf0, buf1);
    {   // last K-step (ks=7): slice already in flight, drain and compute
        asm volatile("s_waitcnt vmcnt(0)" ::: "memory");
        __builtin_amdgcn_s_barrier();
        READ_ALL(buf1);
        asm volatile("s_waitcnt lgkmcnt(0)" ::: "memory");
        __builtin_amdgcn_sched_barrier(0);
        MFMA48;
    }
    __syncthreads();

    // ---- epilogue (round-0 verbatim): C/D row = q*4+reg, col = lane&15 ----
    T2 colT[4];
#pragma unroll
    for (int j = 0; j < 4; j++) colT[j] = t2_sent();
    T2 rowT[4][4];

    const int cb = m0 + wx * 64 + lc;
#pragma unroll
    for (int i = 0; i < 4; i++) {
#pragma unroll
        for (int r = 0; r < 4; r++)
            rowT[i][r] = t2_make4(acc[i][0][r], acc[i][1][r], acc[i][2][r], acc[i][3][r],
                                  cb, cb + 16, cb + 32, cb + 48);
        const int rb = n0 + wy * 64 + i * 16 + q * 4;
#pragma unroll
        for (int j = 0; j < 4; j++)
            colT[j] = t2_merge(colT[j],
                t2_make4(acc[i][j][0], acc[i][j][1], acc[i][j][2], acc[i][j][3],
                         rb, rb + 1, rb + 2, rb + 3));
    }

    // cols: merge across the 4 quads (same column, different row-quarters)
#pragma unroll
    for (int j = 0; j < 4; j++) {
        colT[j] = t2_merge(colT[j], t2_shfl_xor(colT[j], 16));
        colT[j] = t2_merge(colT[j], t2_shfl_xor(colT[j], 32));
        if (q == 0) redC[(wx * 64 + j * 16 + lc) * 2 + wy] = t2_pack(colT[j]);
    }

    // rows: two LDS rounds (by wy), bank-spread slots, free 2-way access
#pragma unroll
    for (int round = 0; round < 2; round++) {
        __syncthreads();
        if (wy == round) {
#pragma unroll
            for (int i = 0; i < 4; i++)
#pragma unroll
                for (int r = 0; r < 4; r++) {
                    int row = i * 16 + q * 4 + r;                 // 0..63
                    int col = (lc << 1) | wx;                     // 0..31
                    int slot = row * 33 + ((col + row + 9 * q) & 31);
                    scrS1[slot] = rowT[i][r].s1;
                    scrS2[slot] = rowT[i][r].s2;
                    scrI[slot]  = rowT[i][r].i1;
                }
        }
        __syncthreads();
        {
            int row = t >> 2, chunk = t & 3;
            T2 a = t2_sent();
#pragma unroll
            for (int s = 0; s < 8; s++) {
                int slot = row * 33 + ((chunk << 3) | s);
                T2 b; b.s1 = scrS1[slot]; b.s2 = scrS2[slot]; b.i1 = scrI[slot];
                a = t2_merge(a, b);
            }
            a = t2_merge(a, t2_shfl_xor(a, 1));
            a = t2_merge(a, t2_shfl_xor(a, 2));
            if (chunk == 0)
                rowPart[(size_t)ctile * NPTS + n0 + round * 64 + row] = t2_pack(a);
        }
    }

    __syncthreads();
    if (t < 128) {
        T2 m = t2_unpack(redC[t * 2 + 0]);
        m = t2_merge(m, t2_unpack(redC[t * 2 + 1]));
        colPart[(size_t)rtile * MPTS + m0 + t] = t2_pack(m);
    }
}

// -------- fused final reduce (round-0 verbatim, proven) --------
__global__ __launch_bounds__(256) void reduce_final(
    const float4* __restrict__ rowPart, const float4* __restrict__ colPart,
    float* __restrict__ out)
{
    __shared__ float4 sh[4][64];
    __shared__ int shFwd[64];
    __shared__ int shOk[64];
    const int t = threadIdx.x, nl = t & 63, sub = t >> 6;
    const int n = blockIdx.x * 64 + nl;

    T2 a = t2_sent();
#pragma unroll
    for (int k = 0; k < 16; k++)
        a = t2_merge(a, t2_unpack(rowPart[(size_t)(sub * 16 + k) * NPTS + n]));
    sh[sub][nl] = t2_pack(a);
    __syncthreads();
    if (t < 64) {
        T2 r = t2_unpack(sh[0][t]);
        r = t2_merge(r, t2_unpack(sh[1][t]));
        r = t2_merge(r, t2_unpack(sh[2][t]));
        r = t2_merge(r, t2_unpack(sh[3][t]));
        float c1 = fmaxf(1.0f - r.s1, 1e-6f), c2 = fmaxf(1.0f - r.s2, 1e-6f);
        float d1 = 1.414213f * sqrtf(c1), d2 = 1.414213f * sqrtf(c2);
        shFwd[t] = r.i1;
        shOk[t]  = ((d1 / d2) < 1.0f) ? 1 : 0;   // exact ref ratio test, RT=1.0
    }
    __syncthreads();
    const int fw = shFwd[nl];
    T2 c = t2_sent();
#pragma unroll
    for (int k = 0; k < 16; k++)
        c = t2_merge(c, t2_unpack(colPart[(size_t)(sub * 16 + k) * MPTS + fw]));
    sh[sub][nl] = t2_pack(c);
    __syncthreads();
    if (t < 64) {
        T2 r = t2_unpack(sh[0][t]);
        r = t2_merge(r, t2_unpack(sh[1][t]));
        r = t2_merge(r, t2_unpack(sh[2][t]));
        r = t2_merge(r, t2_unpack(sh[3][t]));
        float c1 = fmaxf(1.0f - r.s1, 1e-6f), c2 = fmaxf(1.0f - r.s2, 1e-6f);
        float d1 = 1.414213f * sqrtf(c1), d2 = 1.414213f * sqrtf(c2);
        bool bok = (d1 / d2) < 1.0f;
        int nn = blockIdx.x * 64 + t;
        bool mutual = (shOk[t] != 0) && bok && (r.i1 == nn);
        int idx0 = mutual ? shFwd[t] : -1;
        out[nn]             = (float)idx0;                // indices0
        out[NPTS + nn]      = -1.0f;                      // matches1 (all -1)
        out[2 * NPTS + nn]  = (idx0 > 0) ? 1.0f : 0.0f;   // mscores0 (strict >0 ref quirk)
        out[3 * NPTS + nn]  = 0.0f;                       // mscores1
    }
}

extern "C" void kernel_launch(void* const* d_in, const int* in_sizes, int n_in,
                              void* d_out, int out_size, void* d_ws, size_t ws_size,
                              hipStream_t stream)
{
    const float* d0 = (const float*)d_in[0];   // [1, 256, 8192] f32
    const float* d1 = (const float*)d_in[1];   // [1, 256, 8192] f32

    char* ws = (char*)d_ws;
    const size_t matB = (size_t)NPTS * FDIM * sizeof(ushort_t);      // 4 MB
    ushort_t* hiA = (ushort_t*)(ws);
    ushort_t* loA = (ushort_t*)(ws + matB);
    ushort_t* hiB = (ushort_t*)(ws + 2 * matB);
    ushort_t* loB = (ushort_t*)(ws + 3 * matB);
    char* p = ws + 4 * matB;
    const size_t rowBytes = (size_t)TCT * NPTS * sizeof(float4);     // 8 MB
    float4* rowPart = (float4*)p;
    float4* colPart = (float4*)(p + rowBytes);

    dim3 gt(NPTS / 64, FDIM / 64, 2);
    transpose_split<<<gt, 256, 0, stream>>>(d0, d1, hiA, loA, hiB, loB);

    dim3 g1(TCT, TRT);
    gemm_top2<<<g1, 256, 0, stream>>>(hiA, loA, hiB, loB, rowPart, colPart);
    reduce_final<<<NPTS / 64, 256, 0, stream>>>(rowPart, colPart, (float*)d_out);
}

// Round 9
// 184.821 us; speedup vs baseline: 1.2926x; 1.0385x over previous
//
#include <hip/hip_runtime.h>
#include <float.h>

#define NPTS 8192
#define MPTS 8192
#define FDIM 256

#define BM 128
#define BN 128
#define BK 32
#define TCT (MPTS / BN)   /* 64 column tiles */
#define TRT (NPTS / BM)   /* 64 row tiles */

typedef unsigned short ushort_t;
typedef unsigned int u32;
typedef __attribute__((ext_vector_type(8))) short short8;
typedef __attribute__((ext_vector_type(4))) float floatx4;

// ---- top-2-by-similarity (proven): select on RAW s (max); clamp and sqrt
// applied only at the ratio test.
struct T2 { float s1, s2; int i1; };   // s1 >= s2

__device__ __forceinline__ T2 t2_sent() { T2 a; a.s1 = -FLT_MAX; a.s2 = -FLT_MAX; a.i1 = 0; return a; }

__device__ __forceinline__ T2 t2_merge(T2 a, T2 b) {
    T2 r;
    r.s1 = fmaxf(a.s1, b.s1);
    r.i1 = (b.s1 > a.s1) ? b.i1 : a.i1;
    r.s2 = fmaxf(fminf(a.s1, b.s1), fmaxf(a.s2, b.s2));
    return r;
}
__device__ __forceinline__ T2 t2_make4(float v0, float v1, float v2, float v3,
                                       int i0, int i1_, int i2, int i3) {
    float lo01 = fminf(v0, v1), hi01 = fmaxf(v0, v1);
    float lo23 = fminf(v2, v3), hi23 = fmaxf(v2, v3);
    int a01 = (v1 > v0) ? i1_ : i0;
    int a23 = (v3 > v2) ? i3 : i2;
    T2 r;
    r.s1 = fmaxf(hi01, hi23);
    r.i1 = (hi23 > hi01) ? a23 : a01;
    r.s2 = fmaxf(fminf(hi01, hi23), fmaxf(lo01, lo23));
    return r;
}
__device__ __forceinline__ float4 t2_pack(T2 a) {
    return make_float4(a.s1, a.s2, __int_as_float(a.i1), 0.0f);
}
__device__ __forceinline__ T2 t2_unpack(float4 v) {
    T2 a; a.s1 = v.x; a.s2 = v.y; a.i1 = __float_as_int(v.z); return a;
}
__device__ __forceinline__ T2 t2_shfl_xor(T2 a, int m) {
    T2 r; r.s1 = __shfl_xor(a.s1, m); r.s2 = __shfl_xor(a.s2, m); r.i1 = __shfl_xor(a.i1, m);
    return r;
}

__device__ __forceinline__ float bf2f(ushort_t u) {
    union { u32 i; float f; } v; v.i = ((u32)u) << 16; return v.f;
}
__device__ __forceinline__ ushort_t f2bf_rtne(float x) {
    u32 u = __float_as_uint(x);
    u32 r = u + 0x7FFFu + ((u >> 16) & 1u);
    return (ushort_t)(r >> 16);
}

// -------- fused transpose + hi/lo split (round-0 verbatim, proven) --------
__global__ __launch_bounds__(256) void transpose_split(
    const float* __restrict__ s0, const float* __restrict__ s1,
    ushort_t* __restrict__ hi0, ushort_t* __restrict__ lo0,
    ushort_t* __restrict__ hi1, ushort_t* __restrict__ lo1)
{
    __shared__ ushort_t hiS[64][66];
    __shared__ ushort_t loS[64][66];
    const float* src = blockIdx.z ? s1 : s0;
    ushort_t* hiT = blockIdx.z ? hi1 : hi0;
    ushort_t* loT = blockIdx.z ? lo1 : lo0;
    const int t = threadIdx.x;
    const int n0 = blockIdx.x * 64, f0 = blockIdx.y * 64;

#pragma unroll
    for (int p = 0; p < 4; p++) {
        int fl = (t >> 4) + p * 16;          // feature row 0..63
        int nl = (t & 15) * 4;               // 4 consecutive points
        float4 x = *(const float4*)&src[(size_t)(f0 + fl) * NPTS + n0 + nl];
        float xs[4] = {x.x, x.y, x.z, x.w};
#pragma unroll
        for (int e = 0; e < 4; e++) {
            ushort_t hb = f2bf_rtne(xs[e]);
            ushort_t lb = f2bf_rtne(xs[e] - bf2f(hb));
            hiS[nl + e][fl] = hb;            // 66-stride: 2-way banks (free)
            loS[nl + e][fl] = lb;
        }
    }
    __syncthreads();
#pragma unroll
    for (int p = 0; p < 8; p++) {
        int nl = (t >> 5) + p * 8;
        int fp = (t & 31) * 2;
        u32 hw = (u32)hiS[nl][fp] | ((u32)hiS[nl][fp + 1] << 16);
        u32 lw = (u32)loS[nl][fp] | ((u32)loS[nl][fp + 1] << 16);
        size_t o = (size_t)(n0 + nl) * FDIM + f0 + fp;
        *(u32*)&hiT[o] = hw;
        *(u32*)&loT[o] = lw;
    }
}

#define GLDS(g, l) __builtin_amdgcn_global_load_lds( \
    (const __attribute__((address_space(1))) void*)(g), \
    (__attribute__((address_space(3))) void*)(l), 16, 0, 0)

// ---- 128x128 MFMA GEMM + top-2, BK=32 SINGLE-buffer, 3 blocks/CU ----
// Round-9 theory: round 7 proved the staging drain is NOT the binding
// constraint at 2 blocks/CU (counted vmcnt(8) dbuf = 123us vs 118us plain).
// The binding constraint is barrier-locked stall with too little foreign
// work. Fix: shrink LDS to 32 KB (single BK=32 buffer) -> 3 blocks/CU
// (launch_bounds (256,3) = 170 regs/wave). B-frags processed in j-halves
// (bh/bl[2] reused) + sched_barrier pin to keep arch-VGPR demand ~<=140.
// Swizzle for 64-B rows: pos = g ^ ((row>>1)&3), validated rounds 2/7/8
// (262K conflicts = negligible). Per-cell accumulation order (k ascending,
// hh/hl/lh) identical to rounds 0-8 -> bit-identical output.
#define STAGE(k0v) do { \
    _Pragma("unroll") for (int cc = 0; cc < 2; cc++) { \
        int _so = srcOff[cc] + (k0v); \
        char* _lb = smem + ldsOff[cc]; \
        GLDS(bAh + _so, _lb); \
        GLDS(bBh + _so, _lb + 8192); \
        GLDS(bAl + _so, _lb + 16384); \
        GLDS(bBl + _so, _lb + 24576); \
    } \
} while (0)

#define READ_A() do { \
    _Pragma("unroll") for (int i = 0; i < 4; i++) { \
        ah[i] = *(const short8*)(smem + aoff[i]); \
        al[i] = *(const short8*)(smem + 16384 + aoff[i]); \
    } \
} while (0)

#define READ_B2(J0) do { \
    _Pragma("unroll") for (int jj = 0; jj < 2; jj++) { \
        bh[jj] = *(const short8*)(smem + 8192 + boff[(J0) + jj]); \
        bl[jj] = *(const short8*)(smem + 24576 + boff[(J0) + jj]); \
    } \
} while (0)

#define MFMA24(J0) do { \
    _Pragma("unroll") for (int i = 0; i < 4; i++) \
    _Pragma("unroll") for (int jj = 0; jj < 2; jj++) { \
        acc[i][(J0) + jj] = __builtin_amdgcn_mfma_f32_16x16x32_bf16(ah[i], bh[jj], acc[i][(J0) + jj], 0, 0, 0); \
        acc[i][(J0) + jj] = __builtin_amdgcn_mfma_f32_16x16x32_bf16(ah[i], bl[jj], acc[i][(J0) + jj], 0, 0, 0); \
        acc[i][(J0) + jj] = __builtin_amdgcn_mfma_f32_16x16x32_bf16(al[i], bh[jj], acc[i][(J0) + jj], 0, 0, 0); \
    } \
} while (0)

__global__ __launch_bounds__(256, 3) void gemm_top2(
    const ushort_t* __restrict__ hiA, const ushort_t* __restrict__ loA,
    const ushort_t* __restrict__ hiB, const ushort_t* __restrict__ loB,
    float4* __restrict__ rowPart, float4* __restrict__ colPart)
{
    __shared__ char smem[32768];
    // epilogue aliases (staging dead after K-loop + barrier):
    float* scrS1 = (float*)smem;                    // 64*33*4 = 8448 B
    float* scrS2 = (float*)(smem + 8448);
    int*   scrI  = (int*)(smem + 16896);            // ends 25344
    float4* redC = (float4*)(smem + 25600);         // 128*2*16 = 4096 B, ends 29696

    const int t = threadIdx.x;
    const int lane = t & 63, lc = lane & 15, q = lane >> 4;
    const int w = t >> 6, wx = w & 1, wy = w >> 1;
    const int ctile = blockIdx.x, rtile = blockIdx.y;
    const int n0 = rtile * BM, m0 = ctile * BN;

    floatx4 acc[4][4];
#pragma unroll
    for (int i = 0; i < 4; i++)
#pragma unroll
        for (int j = 0; j < 4; j++) acc[i][j] = (floatx4)0.0f;

    // staging map: chunk L = cc*256 + t -> row = L>>2, pos = L&3,
    // global chunk g = pos ^ ((row>>1)&3); LDS dest = L*16 B (lane-contig).
    int srcOff[2], ldsOff[2];
#pragma unroll
    for (int cc = 0; cc < 2; cc++) {
        int L = cc * 256 + t;
        int row = L >> 2;
        int g = (L & 3) ^ ((L >> 3) & 3);
        srcOff[cc] = row * FDIM + g * 8;
        ldsOff[cc] = L * 16;
    }
    const ushort_t* bAh = hiA + (size_t)n0 * FDIM;
    const ushort_t* bAl = loA + (size_t)n0 * FDIM;
    const ushort_t* bBh = hiB + (size_t)m0 * FDIM;
    const ushort_t* bBl = loB + (size_t)m0 * FDIM;

    // fragment byte offsets: row*64 + (q ^ ((row>>1)&3))*16; row = 16m+lc so
    // (row>>1)&3 == (lc>>1)&3, wave-invariant per lane.
    const int xa = (q ^ ((lc >> 1) & 3)) * 16;
    int aoff[4], boff[4];
#pragma unroll
    for (int i = 0; i < 4; i++) {
        aoff[i] = (wy * 64 + i * 16 + lc) * 64 + xa;
        boff[i] = (wx * 64 + i * 16 + lc) * 64 + xa;
    }

    short8 ah[4], al[4], bh[2], bl[2];

#pragma unroll 1
    for (int ks = 0; ks < 8; ks++) {
        if (ks) __syncthreads();             // all waves done reading LDS
        STAGE(ks * BK);
        __syncthreads();                     // staged (compiler drains vmcnt)
        READ_A();
        READ_B2(0);
        MFMA24(0);
        __builtin_amdgcn_sched_barrier(0);   // pin: 2nd B-read after 1st MFMAs
        READ_B2(2);
        MFMA24(2);
    }
    __syncthreads();

    // ---- epilogue (round-0 verbatim): C/D row = q*4+reg, col = lane&15 ----
    T2 colT[4];
#pragma unroll
    for (int j = 0; j < 4; j++) colT[j] = t2_sent();
    T2 rowT[4][4];

    const int cb = m0 + wx * 64 + lc;
#pragma unroll
    for (int i = 0; i < 4; i++) {
#pragma unroll
        for (int r = 0; r < 4; r++)
            rowT[i][r] = t2_make4(acc[i][0][r], acc[i][1][r], acc[i][2][r], acc[i][3][r],
                                  cb, cb + 16, cb + 32, cb + 48);
        const int rb = n0 + wy * 64 + i * 16 + q * 4;
#pragma unroll
        for (int j = 0; j < 4; j++)
            colT[j] = t2_merge(colT[j],
                t2_make4(acc[i][j][0], acc[i][j][1], acc[i][j][2], acc[i][j][3],
                         rb, rb + 1, rb + 2, rb + 3));
    }

    // cols: merge across the 4 quads (same column, different row-quarters)
#pragma unroll
    for (int j = 0; j < 4; j++) {
        colT[j] = t2_merge(colT[j], t2_shfl_xor(colT[j], 16));
        colT[j] = t2_merge(colT[j], t2_shfl_xor(colT[j], 32));
        if (q == 0) redC[(wx * 64 + j * 16 + lc) * 2 + wy] = t2_pack(colT[j]);
    }

    // rows: two LDS rounds (by wy), bank-spread slots, free 2-way access
#pragma unroll
    for (int round = 0; round < 2; round++) {
        __syncthreads();
        if (wy == round) {
#pragma unroll
            for (int i = 0; i < 4; i++)
#pragma unroll
                for (int r = 0; r < 4; r++) {
                    int row = i * 16 + q * 4 + r;                 // 0..63
                    int col = (lc << 1) | wx;                     // 0..31
                    int slot = row * 33 + ((col + row + 9 * q) & 31);
                    scrS1[slot] = rowT[i][r].s1;
                    scrS2[slot] = rowT[i][r].s2;
                    scrI[slot]  = rowT[i][r].i1;
                }
        }
        __syncthreads();
        {
            int row = t >> 2, chunk = t & 3;
            T2 a = t2_sent();
#pragma unroll
            for (int s = 0; s < 8; s++) {
                int slot = row * 33 + ((chunk << 3) | s);
                T2 b; b.s1 = scrS1[slot]; b.s2 = scrS2[slot]; b.i1 = scrI[slot];
                a = t2_merge(a, b);
            }
            a = t2_merge(a, t2_shfl_xor(a, 1));
            a = t2_merge(a, t2_shfl_xor(a, 2));
            if (chunk == 0)
                rowPart[(size_t)ctile * NPTS + n0 + round * 64 + row] = t2_pack(a);
        }
    }

    __syncthreads();
    if (t < 128) {
        T2 m = t2_unpack(redC[t * 2 + 0]);
        m = t2_merge(m, t2_unpack(redC[t * 2 + 1]));
        colPart[(size_t)rtile * MPTS + m0 + t] = t2_pack(m);
    }
}

// -------- fused final reduce (round-0 verbatim, proven) --------
__global__ __launch_bounds__(256) void reduce_final(
    const float4* __restrict__ rowPart, const float4* __restrict__ colPart,
    float* __restrict__ out)
{
    __shared__ float4 sh[4][64];
    __shared__ int shFwd[64];
    __shared__ int shOk[64];
    const int t = threadIdx.x, nl = t & 63, sub = t >> 6;
    const int n = blockIdx.x * 64 + nl;

    T2 a = t2_sent();
#pragma unroll
    for (int k = 0; k < 16; k++)
        a = t2_merge(a, t2_unpack(rowPart[(size_t)(sub * 16 + k) * NPTS + n]));
    sh[sub][nl] = t2_pack(a);
    __syncthreads();
    if (t < 64) {
        T2 r = t2_unpack(sh[0][t]);
        r = t2_merge(r, t2_unpack(sh[1][t]));
        r = t2_merge(r, t2_unpack(sh[2][t]));
        r = t2_merge(r, t2_unpack(sh[3][t]));
        float c1 = fmaxf(1.0f - r.s1, 1e-6f), c2 = fmaxf(1.0f - r.s2, 1e-6f);
        float d1 = 1.414213f * sqrtf(c1), d2 = 1.414213f * sqrtf(c2);
        shFwd[t] = r.i1;
        shOk[t]  = ((d1 / d2) < 1.0f) ? 1 : 0;   // exact ref ratio test, RT=1.0
    }
    __syncthreads();
    const int fw = shFwd[nl];
    T2 c = t2_sent();
#pragma unroll
    for (int k = 0; k < 16; k++)
        c = t2_merge(c, t2_unpack(colPart[(size_t)(sub * 16 + k) * MPTS + fw]));
    sh[sub][nl] = t2_pack(c);
    __syncthreads();
    if (t < 64) {
        T2 r = t2_unpack(sh[0][t]);
        r = t2_merge(r, t2_unpack(sh[1][t]));
        r = t2_merge(r, t2_unpack(sh[2][t]));
        r = t2_merge(r, t2_unpack(sh[3][t]));
        float c1 = fmaxf(1.0f - r.s1, 1e-6f), c2 = fmaxf(1.0f - r.s2, 1e-6f);
        float d1 = 1.414213f * sqrtf(c1), d2 = 1.414213f * sqrtf(c2);
        bool bok = (d1 / d2) < 1.0f;
        int nn = blockIdx.x * 64 + t;
        bool mutual = (shOk[t] != 0) && bok && (r.i1 == nn);
        int idx0 = mutual ? shFwd[t] : -1;
        out[nn]             = (float)idx0;                // indices0
        out[NPTS + nn]      = -1.0f;                      // matches1 (all -1)
        out[2 * NPTS + nn]  = (idx0 > 0) ? 1.0f : 0.0f;   // mscores0 (strict >0 ref quirk)
        out[3 * NPTS + nn]  = 0.0f;                       // mscores1
    }
}

extern "C" void kernel_launch(void* const* d_in, const int* in_sizes, int n_in,
                              void* d_out, int out_size, void* d_ws, size_t ws_size,
                              hipStream_t stream)
{
    const float* d0 = (const float*)d_in[0];   // [1, 256, 8192] f32
    const float* d1 = (const float*)d_in[1];   // [1, 256, 8192] f32

    char* ws = (char*)d_ws;
    const size_t matB = (size_t)NPTS * FDIM * sizeof(ushort_t);      // 4 MB
    ushort_t* hiA = (ushort_t*)(ws);
    ushort_t* loA = (ushort_t*)(ws + matB);
    ushort_t* hiB = (ushort_t*)(ws + 2 * matB);
    ushort_t* loB = (ushort_t*)(ws + 3 * matB);
    char* p = ws + 4 * matB;
    const size_t rowBytes = (size_t)TCT * NPTS * sizeof(float4);     // 8 MB
    float4* rowPart = (float4*)p;
    float4* colPart = (float4*)(p + rowBytes);

    dim3 gt(NPTS / 64, FDIM / 64, 2);
    transpose_split<<<gt, 256, 0, stream>>>(d0, d1, hiA, loA, hiB, loB);

    dim3 g1(TCT, TRT);
    gemm_top2<<<g1, 256, 0, stream>>>(hiA, loA, hiB, loB, rowPart, colPart);
    reduce_final<<<NPTS / 64, 256, 0, stream>>>(rowPart, colPart, (float*)d_out);
}